// Round 6
// baseline (119.657 us; speedup 1.0000x reference)
//
#include <hip/hip_runtime.h>

#define IN_CH 32
#define OUT_CH 32
#define M1 16
#define M2 16
#define H_ 64
#define W_ 33
#define HW (H_*W_)          // 2112
#define BLPB 8              // batch-l elements per compute block

typedef float f2 __attribute__((ext_vector_type(2)));

// complex MAC: acc += x * w  (x = xr + i*xi, w = wr + i*wi), acc packed (re,im)
__device__ __forceinline__ void cmac(f2& acc, float xr, float xi, float wr, float wi) {
    acc = __builtin_elementwise_fma((f2){xr, xr}, (f2){wr, wi}, acc);
    acc = __builtin_elementwise_fma((f2){-xi, xi}, (f2){wi, wr}, acc);
}

// 4 c-steps of complex FMA consuming weight batch WR/WI (float4[4])
#define FMA_BATCH(WR, WI, CB)                                              \
    _Pragma("unroll")                                                      \
    for (int u = 0; u < 4; ++u) {                                          \
        _Pragma("unroll")                                                  \
        for (int bb = 0; bb < 4; ++bb) {                                   \
            const float4* xp = (const float4*)&xs[bh * 4 + bb][(CB) + u][jq * 4]; \
            float4 x01 = xp[0];                                            \
            float4 x23 = xp[1];                                            \
            cmac(acc[bb][0], x01.x, x01.y, WR[u].x, WI[u].x);              \
            cmac(acc[bb][1], x01.z, x01.w, WR[u].y, WI[u].y);              \
            cmac(acc[bb][2], x23.x, x23.y, WR[u].z, WI[u].z);              \
            cmac(acc[bb][3], x23.z, x23.w, WR[u].w, WI[u].w);              \
        }                                                                  \
    }

// 1536 blocks x 256 threads.
//   bid%3==0 (512): compute the two mode regions, BLPB bl per block
//   else     (1024): zero-fill the complement (pure write stream)
__global__ __launch_bounds__(256, 3) void spectral_fused(
    const float* __restrict__ x_re, const float* __restrict__ x_im,
    const float* __restrict__ w1_re, const float* __restrict__ w1_im,
    const float* __restrict__ w2_re, const float* __restrict__ w2_im,
    float* __restrict__ out)
{
    const int tid = threadIdx.x;
    const int bid = blockIdx.x;
    const int role = bid % 3;

    if (role) {
        // ---------------- fill role ----------------
        const int fid = (bid / 3) * 2 + (role - 1);   // [0, 1024)
        const int gtid = fid * 256 + tid;
        const int nthreads = 1024 * 256;

        float4* out4 = (float4*)out;
        const float4 z4 = make_float4(0.f, 0.f, 0.f, 0.f);
        const int totalA = 4096 * 528;                // middle band h in [16,48)
        for (int idx = gtid; idx < totalA; idx += nthreads) {
            int plane = idx / 528;
            int k = idx - plane * 528;
            out4[(long)plane * 1056 + 264 + k] = z4;
        }
        float2* out2 = (float2*)out;
        const float2 z2 = make_float2(0.f, 0.f);
        const int totalB = 4096 * 544;                // w-tails of corner bands
        for (int idx = gtid; idx < totalB; idx += nthreads) {
            int plane = idx / 544;
            int r = idx - plane * 544;
            int hh = r / 17;
            int t = r - hh * 17;
            int h = hh < 16 ? hh : hh + 32;
            out2[(long)plane * 2112 + h * 33 + 16 + t] = z2;
        }
        return;
    }

    // ---------------- compute role ----------------
    const int cid = bid / 3;              // [0, 512)
    const int ri = cid >> 4;              // region*16 + i
    const int chunk = cid & 15;           // 16 chunks of BLPB bl
    const int region = ri >> 4;
    const int i = ri & 15;
    const int h = region ? (48 + i) : i;
    const int bl0 = chunk * BLPB;

    __shared__ __align__(16) float2 xs[BLPB][IN_CH][M2];   // 32 KB

    for (int item = tid; item < BLPB * IN_CH * M2; item += 256) {
        int j = item & 15;
        int c = (item >> 4) & 31;
        int b = item >> 9;
        long src = (long)((bl0 + b) * IN_CH + c) * HW + (long)h * W_ + j;
        xs[b][c][j] = make_float2(x_re[src], x_im[src]);
    }
    __syncthreads();

    // thread = (bh, o, jq): bh = bl half, o = out channel, jq = j quad
    const int bh = tid >> 7;              // [0,2)
    const int o  = (tid >> 2) & 31;       // [0,32)
    const int jq = tid & 3;               // [0,4)

    const float* wreb = region ? w2_re : w1_re;
    const float* wimb = region ? w2_im : w1_im;
    const float4* __restrict__ wre4 = (const float4*)wreb + (o * 64 + i * 4 + jq);
    const float4* __restrict__ wim4 = (const float4*)wimb + (o * 64 + i * 4 + jq);

    f2 acc[4][4];
    #pragma unroll
    for (int bb = 0; bb < 4; ++bb)
        #pragma unroll
        for (int jj = 0; jj < 4; ++jj)
            acc[bb][jj] = (f2){0.f, 0.f};

    // Register double-buffered weight pipeline: 8 float4 (128B/thread) always
    // in flight behind a full compiler fence while the previous 4-c batch's
    // 256 FMAs execute.
    float4 wrA[4], wiA[4], wrB[4], wiB[4];
    #pragma unroll
    for (int u = 0; u < 4; ++u) {
        wrA[u] = wre4[u * 2048];
        wiA[u] = wim4[u * 2048];
    }

    #pragma unroll 1
    for (int cb2 = 0; cb2 < 4; ++cb2) {
        const int c0 = cb2 * 8;
        #pragma unroll
        for (int u = 0; u < 4; ++u) {
            wrB[u] = wre4[(c0 + 4 + u) * 2048];
            wiB[u] = wim4[(c0 + 4 + u) * 2048];
        }
        asm volatile("" ::: "memory");
        FMA_BATCH(wrA, wiA, c0);
        if (cb2 < 3) {
            #pragma unroll
            for (int u = 0; u < 4; ++u) {
                wrA[u] = wre4[(c0 + 8 + u) * 2048];
                wiA[u] = wim4[(c0 + 8 + u) * 2048];
            }
        }
        asm volatile("" ::: "memory");
        FMA_BATCH(wrB, wiB, c0 + 4);
    }

    float2* out2 = (float2*)out;
    #pragma unroll
    for (int bb = 0; bb < 4; ++bb) {
        int bl = bl0 + bh * 4 + bb;
        long rowbase = ((long)(bl * OUT_CH + o) * H_ + h) * W_ + jq * 4;  // float2 units
        #pragma unroll
        for (int jj = 0; jj < 4; ++jj)
            out2[rowbase + jj] = make_float2(acc[bb][jj].x, acc[bb][jj].y);
    }
}

extern "C" void kernel_launch(void* const* d_in, const int* in_sizes, int n_in,
                              void* d_out, int out_size, void* d_ws, size_t ws_size,
                              hipStream_t stream) {
    const float* x_re  = (const float*)d_in[0];
    const float* x_im  = (const float*)d_in[1];
    const float* w1_re = (const float*)d_in[2];
    const float* w1_im = (const float*)d_in[3];
    const float* w2_re = (const float*)d_in[4];
    const float* w2_im = (const float*)d_in[5];
    float* out = (float*)d_out;

    spectral_fused<<<dim3(1536), dim3(256), 0, stream>>>(
        x_re, x_im, w1_re, w1_im, w2_re, w2_im, out);
}

// Round 7
// 57.778 us; speedup vs baseline: 2.0710x; 2.0710x over previous
//
#include <hip/hip_runtime.h>

#define HW 2112L            // 64*33
typedef float f32x4 __attribute__((ext_vector_type(4)));
typedef short s16x8 __attribute__((ext_vector_type(8)));

// ---- d_ws layout (bytes). XT planes: 512 modes * 8 mtiles * 512 elem * 2B.
#define XT_PLANE 4194304L
#define WT_PLANE 1048576L   // 512 modes * 2 ntiles * 512 * 2B
#define OFF_XHR 0L
#define OFF_XLR (XT_PLANE)
#define OFF_XHI (2*XT_PLANE)
#define OFF_XLI (3*XT_PLANE)
#define OFF_WHR (4*XT_PLANE)
#define OFF_WLR (4*XT_PLANE + WT_PLANE)
#define OFF_WHI (4*XT_PLANE + 2*WT_PLANE)
#define OFF_WLI (4*XT_PLANE + 3*WT_PLANE)

__device__ __forceinline__ ushort f2bf(float f) {
    unsigned u = __float_as_uint(f);
    u += 0x7FFF + ((u >> 16) & 1);          // RNE to bf16
    return (ushort)(u >> 16);
}
__device__ __forceinline__ void split_bf(float v, ushort& hi, ushort& lo) {
    hi = f2bf(v);
    float hf = __uint_as_float(((unsigned)hi) << 16);
    lo = f2bf(v - hf);
}

// =============== Kernel A: fragment-order transpose + middle-band fill ===============
// bid <  256 : X transform. block=(r,i,mt). Stage 16bl x 32c x 16j slice in LDS,
//              emit bf16 hi/lo planes so lane l's A-frag is ws[... + l*16B].
// bid <  320 : W transform. block=(r,i,nt). Emit B-frag planes likewise.
// bid >= 320 : zero middle band h in [16,48) (512 blocks, float4 stream).
__global__ __launch_bounds__(256) void spectral_prep(
    const float* __restrict__ x_re, const float* __restrict__ x_im,
    const float* __restrict__ w1_re, const float* __restrict__ w1_im,
    const float* __restrict__ w2_re, const float* __restrict__ w2_im,
    float* __restrict__ out, char* __restrict__ ws)
{
    const int tid = threadIdx.x;
    const int bid = blockIdx.x;
    __shared__ float lds[32][16][17];        // [c][blrow][j+pad] ~34.8 KB

    if (bid < 256) {
        const int r = bid >> 7, i = (bid >> 3) & 15, mt = bid & 7;
        const int h = r ? 48 + i : i;
        const int j = tid >> 4, row = tid & 15;
        const int modeLin = (r * 16 + i) * 16 + j;
        #pragma unroll 1
        for (int pass = 0; pass < 2; ++pass) {
            const float* src = pass ? x_im : x_re;
            if (pass) __syncthreads();
            for (int it = 0; it < 32; ++it) {
                int idx = it * 256 + tid;
                int jj = idx & 15, rr = idx >> 4;        // rr in [0,512)
                int c = rr >> 4, rw = rr & 15;
                int bl = mt * 16 + rw;
                lds[c][rw][jj] = src[(long)(bl * 32 + c) * HW + h * 33 + jj];
            }
            __syncthreads();
            s16x8* ph = (s16x8*)(ws + (pass ? OFF_XHI : OFF_XHR));
            s16x8* pl = (s16x8*)(ws + (pass ? OFF_XLI : OFF_XLR));
            #pragma unroll
            for (int kg = 0; kg < 4; ++kg) {
                s16x8 vh, vl;
                #pragma unroll
                for (int e = 0; e < 8; ++e) {
                    ushort a, b;
                    split_bf(lds[kg * 8 + e][row][j], a, b);
                    vh[e] = (short)a; vl[e] = (short)b;
                }
                long off = (long)(modeLin * 8 + mt) * 64 + kg * 16 + row;  // s16x8 units
                ph[off] = vh;
                pl[off] = vl;
            }
        }
    } else if (bid < 320) {
        const int widx = bid - 256;
        const int r = widx >> 5, i = (widx >> 1) & 15, nt = widx & 1;
        const float* wre = r ? w2_re : w1_re;
        const float* wim = r ? w2_im : w1_im;
        const int j = tid >> 4, col = tid & 15, o = nt * 16 + col;
        const int modeLin = (r * 16 + i) * 16 + j;
        s16x8* phr = (s16x8*)(ws + OFF_WHR);
        s16x8* plr = (s16x8*)(ws + OFF_WLR);
        s16x8* phi = (s16x8*)(ws + OFF_WHI);
        s16x8* pli = (s16x8*)(ws + OFF_WLI);
        #pragma unroll
        for (int kg = 0; kg < 4; ++kg) {
            s16x8 hr, lr, hi2, li2;
            #pragma unroll
            for (int e = 0; e < 8; ++e) {
                int c = kg * 8 + e;
                long src = ((long)(c * 32 + o) * 16 + i) * 16 + j;
                ushort a, b;
                split_bf(wre[src], a, b); hr[e] = (short)a; lr[e] = (short)b;
                split_bf(wim[src], a, b); hi2[e] = (short)a; li2[e] = (short)b;
            }
            long off = (long)(modeLin * 2 + nt) * 64 + kg * 16 + col;
            phr[off] = hr; plr[off] = lr; phi[off] = hi2; pli[off] = li2;
        }
    } else {
        const int fid = bid - 320;                    // [0,512)
        int gtid = fid * 256 + tid, n = 512 * 256;
        float4* out4 = (float4*)out;
        const float4 z = make_float4(0.f, 0.f, 0.f, 0.f);
        for (int idx = gtid; idx < 4096 * 528; idx += n) {
            int plane = idx / 528;
            int k = idx - plane * 528;
            out4[(long)plane * 1056 + 264 + k] = z;
        }
    }
}

// =============== Kernel B: batched MFMA GEMM + tail fill ===============
// bid < 512: block=(r,i,j). 4 waves x 2 mtiles x 2 ntiles; 12 MFMA per tile
//            (bf16 hi/lo 3-term split, re = P - N, im = I).
// bid >= 512: zero w-tails of the two corner bands.
__global__ __launch_bounds__(256) void spectral_mfma(
    float* __restrict__ out, const char* __restrict__ ws)
{
    const int tid = threadIdx.x, bid = blockIdx.x;

    if (bid >= 512) {
        const int fid = bid - 512;
        int gtid = fid * 256 + tid, n = 512 * 256;
        float2* out2 = (float2*)out;
        const float2 z = make_float2(0.f, 0.f);
        for (int idx = gtid; idx < 4096 * 544; idx += n) {
            int plane = idx / 544;
            int rr = idx - plane * 544;
            int hh = rr / 17, t = rr - hh * 17;
            int h = hh < 16 ? hh : hh + 32;
            out2[(long)plane * 2112 + h * 33 + 16 + t] = z;
        }
        return;
    }

    const int r = bid >> 8, i = (bid >> 4) & 15, j = bid & 15;
    const int h = r ? 48 + i : i;
    const int modeLin = (r * 16 + i) * 16 + j;
    const int wave = tid >> 6, lane = tid & 63;

    const s16x8* Axhr = (const s16x8*)(ws + OFF_XHR);
    const s16x8* Axlr = (const s16x8*)(ws + OFF_XLR);
    const s16x8* Axhi = (const s16x8*)(ws + OFF_XHI);
    const s16x8* Axli = (const s16x8*)(ws + OFF_XLI);
    const s16x8* Bwhr = (const s16x8*)(ws + OFF_WHR);
    const s16x8* Bwlr = (const s16x8*)(ws + OFF_WLR);
    const s16x8* Bwhi = (const s16x8*)(ws + OFF_WHI);
    const s16x8* Bwli = (const s16x8*)(ws + OFF_WLI);

    s16x8 Bhr[2], Blr[2], Bhi[2], Bli[2];
    #pragma unroll
    for (int nt = 0; nt < 2; ++nt) {
        long boff = (long)(modeLin * 2 + nt) * 64 + lane;
        Bhr[nt] = Bwhr[boff]; Blr[nt] = Bwlr[boff];
        Bhi[nt] = Bwhi[boff]; Bli[nt] = Bwli[boff];
    }

    f32x4 accP[2][2], accN[2][2], accI[2][2];
    #pragma unroll
    for (int m = 0; m < 2; ++m)
        #pragma unroll
        for (int nt = 0; nt < 2; ++nt) {
            accP[m][nt] = (f32x4)0.0f; accN[m][nt] = (f32x4)0.0f; accI[m][nt] = (f32x4)0.0f;
        }

    #pragma unroll
    for (int m = 0; m < 2; ++m) {
        const int mt = wave * 2 + m;
        long aoff = (long)(modeLin * 8 + mt) * 64 + lane;
        s16x8 Ahr = Axhr[aoff], Alr = Axlr[aoff];
        s16x8 Ahi = Axhi[aoff], Ali = Axli[aoff];
        #pragma unroll
        for (int nt = 0; nt < 2; ++nt) {
            // P = Ar*Br (3-term), N = Ai*Bi (3-term), I = Ar*Bi + Ai*Br (6-term)
            accP[m][nt] = __builtin_amdgcn_mfma_f32_16x16x32_bf16(Ahr, Bhr[nt], accP[m][nt], 0, 0, 0);
            accP[m][nt] = __builtin_amdgcn_mfma_f32_16x16x32_bf16(Ahr, Blr[nt], accP[m][nt], 0, 0, 0);
            accP[m][nt] = __builtin_amdgcn_mfma_f32_16x16x32_bf16(Alr, Bhr[nt], accP[m][nt], 0, 0, 0);
            accN[m][nt] = __builtin_amdgcn_mfma_f32_16x16x32_bf16(Ahi, Bhi[nt], accN[m][nt], 0, 0, 0);
            accN[m][nt] = __builtin_amdgcn_mfma_f32_16x16x32_bf16(Ahi, Bli[nt], accN[m][nt], 0, 0, 0);
            accN[m][nt] = __builtin_amdgcn_mfma_f32_16x16x32_bf16(Ali, Bhi[nt], accN[m][nt], 0, 0, 0);
            accI[m][nt] = __builtin_amdgcn_mfma_f32_16x16x32_bf16(Ahr, Bhi[nt], accI[m][nt], 0, 0, 0);
            accI[m][nt] = __builtin_amdgcn_mfma_f32_16x16x32_bf16(Ahr, Bli[nt], accI[m][nt], 0, 0, 0);
            accI[m][nt] = __builtin_amdgcn_mfma_f32_16x16x32_bf16(Alr, Bhi[nt], accI[m][nt], 0, 0, 0);
            accI[m][nt] = __builtin_amdgcn_mfma_f32_16x16x32_bf16(Ahi, Bhr[nt], accI[m][nt], 0, 0, 0);
            accI[m][nt] = __builtin_amdgcn_mfma_f32_16x16x32_bf16(Ahi, Blr[nt], accI[m][nt], 0, 0, 0);
            accI[m][nt] = __builtin_amdgcn_mfma_f32_16x16x32_bf16(Ali, Bhr[nt], accI[m][nt], 0, 0, 0);
        }
    }

    // D layout (verified m89/m91): col = lane&15, row = (lane>>4)*4 + reg
    float2* out2 = (float2*)out;
    const int colo = lane & 15, rbase = (lane >> 4) * 4;
    #pragma unroll
    for (int m = 0; m < 2; ++m) {
        const int mt = wave * 2 + m;
        #pragma unroll
        for (int nt = 0; nt < 2; ++nt) {
            const int o = nt * 16 + colo;
            #pragma unroll
            for (int q = 0; q < 4; ++q) {
                int bl = mt * 16 + rbase + q;
                long dst = ((long)(bl * 32 + o) * 64 + h) * 33 + j;
                out2[dst] = make_float2(accP[m][nt][q] - accN[m][nt][q], accI[m][nt][q]);
            }
        }
    }
}

extern "C" void kernel_launch(void* const* d_in, const int* in_sizes, int n_in,
                              void* d_out, int out_size, void* d_ws, size_t ws_size,
                              hipStream_t stream) {
    const float* x_re  = (const float*)d_in[0];
    const float* x_im  = (const float*)d_in[1];
    const float* w1_re = (const float*)d_in[2];
    const float* w1_im = (const float*)d_in[3];
    const float* w2_re = (const float*)d_in[4];
    const float* w2_im = (const float*)d_in[5];
    float* out = (float*)d_out;
    char* ws = (char*)d_ws;

    spectral_prep<<<dim3(832), dim3(256), 0, stream>>>(
        x_re, x_im, w1_re, w1_im, w2_re, w2_im, out, ws);
    spectral_mfma<<<dim3(1024), dim3(256), 0, stream>>>(out, ws);
}

// Round 8
// 39.992 us; speedup vs baseline: 2.9920x; 1.4447x over previous
//
#include <hip/hip_runtime.h>

#define HW 2112L            // 64*33
typedef float f32x4 __attribute__((ext_vector_type(4)));
typedef short s16x8 __attribute__((ext_vector_type(8)));

// ws: W B-fragment planes only. 512 modes * 2 ntiles * 64 lanes * 8 bf16 * 2B = 1 MB/plane.
#define WT_PLANE 1048576L
#define OFF_WHR 0L
#define OFF_WLR (WT_PLANE)
#define OFF_WHI (2*WT_PLANE)
#define OFF_WLI (3*WT_PLANE)

__device__ __forceinline__ ushort f2bf(float f) {
    unsigned u = __float_as_uint(f);
    u += 0x7FFF + ((u >> 16) & 1);          // RNE to bf16
    return (ushort)(u >> 16);
}
__device__ __forceinline__ void split_bf(float v, ushort& hi, ushort& lo) {
    hi = f2bf(v);
    float hf = __uint_as_float(((unsigned)hi) << 16);
    lo = f2bf(v - hf);
}

// =============== Kernel A: W -> B-fragment planes (64 blocks, tiny) ===============
// block=(r,i,nt). Lane layout: frag[e] = w[c=kg*8+e][o=nt*16+col], kg=lane>>4, col=lane&15.
__global__ __launch_bounds__(256) void w_prep(
    const float* __restrict__ w1_re, const float* __restrict__ w1_im,
    const float* __restrict__ w2_re, const float* __restrict__ w2_im,
    char* __restrict__ ws)
{
    const int tid = threadIdx.x, bid = blockIdx.x;
    const int r = bid >> 5, i = (bid >> 1) & 15, nt = bid & 1;
    const float* wre = r ? w2_re : w1_re;
    const float* wim = r ? w2_im : w1_im;
    const int j = tid >> 4, col = tid & 15, o = nt * 16 + col;
    const int modeLin = (r * 16 + i) * 16 + j;
    s16x8* phr = (s16x8*)(ws + OFF_WHR);
    s16x8* plr = (s16x8*)(ws + OFF_WLR);
    s16x8* phi = (s16x8*)(ws + OFF_WHI);
    s16x8* pli = (s16x8*)(ws + OFF_WLI);
    #pragma unroll
    for (int kg = 0; kg < 4; ++kg) {
        s16x8 hr, lr, hi2, li2;
        #pragma unroll
        for (int e = 0; e < 8; ++e) {
            int c = kg * 8 + e;
            long src = ((long)(c * 32 + o) * 16 + i) * 16 + j;
            ushort a, b;
            split_bf(wre[src], a, b); hr[e] = (short)a; lr[e] = (short)b;
            split_bf(wim[src], a, b); hi2[e] = (short)a; li2[e] = (short)b;
        }
        long off = (long)(modeLin * 2 + nt) * 64 + kg * 16 + col;
        phr[off] = hr; plr[off] = lr; phi[off] = hi2; pli[off] = li2;
    }
}

// =============== Kernel B: fused transform + MFMA GEMM + row-contiguous epilogue ===============
// 512 blocks x 256 threads.
//   even bid (256): block=(r,i,bltile16). LDS-stage x slice, gather A-frags, 24 MFMA/j,
//                   stage results in LDS, write full 33-float2 rows (tail zeros fused).
//   odd bid  (256): zero middle band h in [16,48) (float4 stream).
__global__ __launch_bounds__(256) void spectral_main(
    const float* __restrict__ x_re, const float* __restrict__ x_im,
    float* __restrict__ out, const char* __restrict__ ws)
{
    const int tid = threadIdx.x, bid = blockIdx.x;

    if (bid & 1) {
        // ---- fill role: middle band ----
        const int fid = bid >> 1;
        int gtid = fid * 256 + tid, n = 256 * 256;
        float4* out4 = (float4*)out;
        const float4 z = make_float4(0.f, 0.f, 0.f, 0.f);
        for (int idx = gtid; idx < 4096 * 528; idx += n) {
            int plane = idx / 528;
            int k = idx - plane * 528;
            out4[(long)plane * 1056 + 264 + k] = z;
        }
        return;
    }

    const int gid = bid >> 1;             // [0,256)
    const int r = gid >> 7, i = (gid >> 3) & 15, bt = gid & 7;
    const int h = r ? 48 + i : i;
    const int bl0 = bt * 16;
    const int modeBase = (r * 16 + i) * 16;

    // LDS: phase 1 = x staging [c 32][bl 16][j 17pad] float2; phase 2 = out staging
    // [row 512][k 17pad] float2. Both exactly 69632 B -> aliased.
    __shared__ __align__(16) char smem[69632];
    float2 (*xls)[16][17] = reinterpret_cast<float2(*)[16][17]>(smem);
    float2 (*stg)[17]     = reinterpret_cast<float2(*)[17]>(smem);

    // ---- stage x[bl0..+16, all c, h, j<16] as interleaved float2 ----
    for (int it = 0; it < 32; ++it) {
        int idx = it * 256 + tid;
        int j = idx & 15, rowid = idx >> 4;        // [0,512)
        int c = rowid >> 4, bl = rowid & 15;
        long src = ((long)(bl0 + bl) * 32 + c) * HW + h * 33 + j;
        xls[c][bl][j] = make_float2(x_re[src], x_im[src]);
    }
    __syncthreads();

    const int wave = tid >> 6, lane = tid & 63;
    const int m = lane & 15, ks = lane >> 4;

    const s16x8* Bwhr = (const s16x8*)(ws + OFF_WHR);
    const s16x8* Bwlr = (const s16x8*)(ws + OFF_WLR);
    const s16x8* Bwhi = (const s16x8*)(ws + OFF_WHI);
    const s16x8* Bwli = (const s16x8*)(ws + OFF_WLI);

    float2 res[4][2][4];                  // [jj][nt][q]

    #pragma unroll
    for (int jj = 0; jj < 4; ++jj) {
        const int j = wave * 4 + jj;
        const int modeLin = modeBase + j;

        // gather A-frags from LDS (lane: bl=m, c=ks*8+e), split to bf16 hi/lo
        s16x8 Ahr, Alr, Ahi, Ali;
        #pragma unroll
        for (int e = 0; e < 8; ++e) {
            float2 v = xls[ks * 8 + e][m][j];
            ushort a, b;
            split_bf(v.x, a, b); Ahr[e] = (short)a; Alr[e] = (short)b;
            split_bf(v.y, a, b); Ahi[e] = (short)a; Ali[e] = (short)b;
        }

        #pragma unroll
        for (int nt = 0; nt < 2; ++nt) {
            long boff = (long)(modeLin * 2 + nt) * 64 + lane;
            s16x8 Bhr = Bwhr[boff], Blr = Bwlr[boff];
            s16x8 Bhi = Bwhi[boff], Bli = Bwli[boff];

            f32x4 accP = (f32x4)0.0f, accN = (f32x4)0.0f, accI = (f32x4)0.0f;
            accP = __builtin_amdgcn_mfma_f32_16x16x32_bf16(Ahr, Bhr, accP, 0, 0, 0);
            accP = __builtin_amdgcn_mfma_f32_16x16x32_bf16(Ahr, Blr, accP, 0, 0, 0);
            accP = __builtin_amdgcn_mfma_f32_16x16x32_bf16(Alr, Bhr, accP, 0, 0, 0);
            accN = __builtin_amdgcn_mfma_f32_16x16x32_bf16(Ahi, Bhi, accN, 0, 0, 0);
            accN = __builtin_amdgcn_mfma_f32_16x16x32_bf16(Ahi, Bli, accN, 0, 0, 0);
            accN = __builtin_amdgcn_mfma_f32_16x16x32_bf16(Ali, Bhi, accN, 0, 0, 0);
            accI = __builtin_amdgcn_mfma_f32_16x16x32_bf16(Ahr, Bhi, accI, 0, 0, 0);
            accI = __builtin_amdgcn_mfma_f32_16x16x32_bf16(Ahr, Bli, accI, 0, 0, 0);
            accI = __builtin_amdgcn_mfma_f32_16x16x32_bf16(Alr, Bhi, accI, 0, 0, 0);
            accI = __builtin_amdgcn_mfma_f32_16x16x32_bf16(Ahi, Bhr, accI, 0, 0, 0);
            accI = __builtin_amdgcn_mfma_f32_16x16x32_bf16(Ahi, Blr, accI, 0, 0, 0);
            accI = __builtin_amdgcn_mfma_f32_16x16x32_bf16(Ali, Bhr, accI, 0, 0, 0);

            #pragma unroll
            for (int q = 0; q < 4; ++q)
                res[jj][nt][q] = make_float2(accP[q] - accN[q], accI[q]);
        }
    }
    __syncthreads();   // all xls reads done -> safe to alias as stg

    // ---- stage results: D layout col=lane&15 (o), row=(lane>>4)*4+q (bl) ----
    const int rbase = (lane >> 4) * 4, colo = lane & 15;
    #pragma unroll
    for (int jj = 0; jj < 4; ++jj)
        #pragma unroll
        for (int nt = 0; nt < 2; ++nt)
            #pragma unroll
            for (int q = 0; q < 4; ++q)
                stg[(rbase + q) * 32 + nt * 16 + colo][wave * 4 + jj] = res[jj][nt][q];
    __syncthreads();

    // ---- row-contiguous write-out: 512 rows x 33 float2, tail zeros fused ----
    float2* out2 = (float2*)out;
    #pragma unroll 2
    for (int t = 0; t < 66; ++t) {
        int idx = t * 256 + tid;              // [0, 16896)
        int row = idx / 33;
        int k = idx - row * 33;
        int bl = row >> 5, o = row & 31;
        float2 v = (k < 16) ? stg[row][k] : make_float2(0.f, 0.f);
        long dst = (((long)(bl0 + bl) * 32 + o) * 64 + h) * 33 + k;
        out2[dst] = v;
    }
}

extern "C" void kernel_launch(void* const* d_in, const int* in_sizes, int n_in,
                              void* d_out, int out_size, void* d_ws, size_t ws_size,
                              hipStream_t stream) {
    const float* x_re  = (const float*)d_in[0];
    const float* x_im  = (const float*)d_in[1];
    const float* w1_re = (const float*)d_in[2];
    const float* w1_im = (const float*)d_in[3];
    const float* w2_re = (const float*)d_in[4];
    const float* w2_im = (const float*)d_in[5];
    float* out = (float*)d_out;
    char* ws = (char*)d_ws;

    w_prep<<<dim3(64), dim3(256), 0, stream>>>(w1_re, w1_im, w2_re, w2_im, ws);
    spectral_main<<<dim3(512), dim3(256), 0, stream>>>(x_re, x_im, out, ws);
}

// Round 9
// 34.679 us; speedup vs baseline: 3.4504x; 1.1532x over previous
//
#include <hip/hip_runtime.h>

#define HW 2112L            // 64*33
typedef float f32x4 __attribute__((ext_vector_type(4)));
typedef short s16x8 __attribute__((ext_vector_type(8)));

// ws: W B-fragment planes. 512 modes * 2 ntiles * 64 lanes * 8 bf16 * 2B = 1 MB/plane.
#define WT_PLANE 1048576L
#define OFF_WHR 0L
#define OFF_WLR (WT_PLANE)
#define OFF_WHI (2*WT_PLANE)
#define OFF_WLI (3*WT_PLANE)

__device__ __forceinline__ ushort f2bf(float f) {
    unsigned u = __float_as_uint(f);
    u += 0x7FFF + ((u >> 16) & 1);          // RNE to bf16
    return (ushort)(u >> 16);
}
__device__ __forceinline__ void split_bf(float v, ushort& hi, ushort& lo) {
    hi = f2bf(v);
    float hf = __uint_as_float(((unsigned)hi) << 16);
    lo = f2bf(v - hf);
}

// =============== Kernel A: W -> B-fragment planes (128 blocks) ===============
// block=(r,i,nt,kgh). frag[e] = w[c=kg*8+e][o=nt*16+col], lane=(kg&1 half via kgh).
__global__ __launch_bounds__(256) void w_prep(
    const float* __restrict__ w1_re, const float* __restrict__ w1_im,
    const float* __restrict__ w2_re, const float* __restrict__ w2_im,
    char* __restrict__ ws)
{
    const int tid = threadIdx.x, bid = blockIdx.x;
    const int r = bid >> 6, i = (bid >> 2) & 15, nt = (bid >> 1) & 1, kh = bid & 1;
    const float* wre = r ? w2_re : w1_re;
    const float* wim = r ? w2_im : w1_im;
    const int j = tid >> 4, col = tid & 15, o = nt * 16 + col;
    const int modeLin = (r * 16 + i) * 16 + j;
    s16x8* phr = (s16x8*)(ws + OFF_WHR);
    s16x8* plr = (s16x8*)(ws + OFF_WLR);
    s16x8* phi = (s16x8*)(ws + OFF_WHI);
    s16x8* pli = (s16x8*)(ws + OFF_WLI);
    #pragma unroll
    for (int kk = 0; kk < 2; ++kk) {
        const int kg = kh * 2 + kk;
        s16x8 hr, lr, hi2, li2;
        #pragma unroll
        for (int e = 0; e < 8; ++e) {
            int c = kg * 8 + e;
            long src = ((long)(c * 32 + o) * 16 + i) * 16 + j;
            ushort a, b;
            split_bf(wre[src], a, b); hr[e] = (short)a; lr[e] = (short)b;
            split_bf(wim[src], a, b); hi2[e] = (short)a; li2[e] = (short)b;
        }
        long off = (long)(modeLin * 2 + nt) * 64 + kg * 16 + col;
        phr[off] = hr; plr[off] = lr; phi[off] = hi2; pli[off] = li2;
    }
}

// =============== Kernel B: fused transform + MFMA + row-contiguous epilogue ===============
// 768 blocks x 256 threads:
//   bid%3 < 2 (512): compute. block=(r,i,bltile8). 34.8KB LDS -> 3-4 blocks/CU.
//   bid%3 == 2 (256): zero middle band h in [16,48) (float4 stream).
__global__ __launch_bounds__(256, 3) void spectral_main(
    const float* __restrict__ x_re, const float* __restrict__ x_im,
    float* __restrict__ out, const char* __restrict__ ws)
{
    const int tid = threadIdx.x, bid = blockIdx.x;
    const int role = bid % 3;

    if (role == 2) {
        // ---- fill role: middle band ----
        const int fid = bid / 3;
        int gtid = fid * 256 + tid, n = 256 * 256;
        float4* out4 = (float4*)out;
        const float4 z = make_float4(0.f, 0.f, 0.f, 0.f);
        for (int idx = gtid; idx < 4096 * 528; idx += n) {
            int plane = idx / 528;
            int k = idx - plane * 528;
            out4[(long)plane * 1056 + 264 + k] = z;
        }
        return;
    }

    const int cid = (bid / 3) * 2 + role;   // [0,512)
    const int r = cid >> 8, i = (cid >> 4) & 15, bt = cid & 15;
    const int h = r ? 48 + i : i;
    const int bl0 = bt * 8;
    const int modeBase = (r * 16 + i) * 16;

    // LDS: phase 1 = xls[c 32][bl 8][j 17pad] float2; phase 2 = stg[row 256][k 17pad]
    // float2. Both 34816 B -> aliased.
    __shared__ __align__(16) char smem[34816];
    float2 (*xls)[8][17] = reinterpret_cast<float2(*)[8][17]>(smem);
    float2 (*stg)[17]    = reinterpret_cast<float2(*)[17]>(smem);

    // ---- stage x[bl0..+8, all c, h, j<16]; 4 indep loads per array per step ----
    #pragma unroll
    for (int p = 0; p < 4; ++p) {
        int idx = p * 256 + tid;            // [0,1024)
        int j4 = idx & 3, row = idx >> 2;   // row: c=row>>3, bl=row&7
        int c = row >> 3, bl = row & 7;
        long base = ((long)((bl0 + bl) * 32 + c)) * HW + h * 33 + j4 * 4;
        float r0 = x_re[base + 0], r1 = x_re[base + 1], r2 = x_re[base + 2], r3 = x_re[base + 3];
        float i0 = x_im[base + 0], i1 = x_im[base + 1], i2 = x_im[base + 2], i3 = x_im[base + 3];
        xls[c][bl][j4 * 4 + 0] = make_float2(r0, i0);
        xls[c][bl][j4 * 4 + 1] = make_float2(r1, i1);
        xls[c][bl][j4 * 4 + 2] = make_float2(r2, i2);
        xls[c][bl][j4 * 4 + 3] = make_float2(r3, i3);
    }
    __syncthreads();

    const int wave = tid >> 6, lane = tid & 63;
    const int m = lane & 7;                 // bl row (rows 8-15 duplicate 0-7, never stored)
    const int ks = lane >> 4;

    const s16x8* Bwhr = (const s16x8*)(ws + OFF_WHR);
    const s16x8* Bwlr = (const s16x8*)(ws + OFF_WLR);
    const s16x8* Bwhi = (const s16x8*)(ws + OFF_WHI);
    const s16x8* Bwli = (const s16x8*)(ws + OFF_WLI);

    float2 res[4][2][4];                    // [jj][nt][q]

    #pragma unroll
    for (int jj = 0; jj < 4; ++jj) {
        const int j = wave * 4 + jj;
        const int modeLin = modeBase + j;

        // gather A-frags from LDS (lane: bl=m, c=ks*8+e), split to bf16 hi/lo
        s16x8 Ahr, Alr, Ahi, Ali;
        #pragma unroll
        for (int e = 0; e < 8; ++e) {
            float2 v = xls[ks * 8 + e][m][j];
            ushort a, b;
            split_bf(v.x, a, b); Ahr[e] = (short)a; Alr[e] = (short)b;
            split_bf(v.y, a, b); Ahi[e] = (short)a; Ali[e] = (short)b;
        }

        #pragma unroll
        for (int nt = 0; nt < 2; ++nt) {
            long boff = (long)(modeLin * 2 + nt) * 64 + lane;
            s16x8 Bhr = Bwhr[boff], Blr = Bwlr[boff];
            s16x8 Bhi = Bwhi[boff], Bli = Bwli[boff];

            f32x4 accP = (f32x4)0.0f, accN = (f32x4)0.0f, accI = (f32x4)0.0f;
            accP = __builtin_amdgcn_mfma_f32_16x16x32_bf16(Ahr, Bhr, accP, 0, 0, 0);
            accP = __builtin_amdgcn_mfma_f32_16x16x32_bf16(Ahr, Blr, accP, 0, 0, 0);
            accP = __builtin_amdgcn_mfma_f32_16x16x32_bf16(Alr, Bhr, accP, 0, 0, 0);
            accN = __builtin_amdgcn_mfma_f32_16x16x32_bf16(Ahi, Bhi, accN, 0, 0, 0);
            accN = __builtin_amdgcn_mfma_f32_16x16x32_bf16(Ahi, Bli, accN, 0, 0, 0);
            accN = __builtin_amdgcn_mfma_f32_16x16x32_bf16(Ali, Bhi, accN, 0, 0, 0);
            accI = __builtin_amdgcn_mfma_f32_16x16x32_bf16(Ahr, Bhi, accI, 0, 0, 0);
            accI = __builtin_amdgcn_mfma_f32_16x16x32_bf16(Ahr, Bli, accI, 0, 0, 0);
            accI = __builtin_amdgcn_mfma_f32_16x16x32_bf16(Alr, Bhi, accI, 0, 0, 0);
            accI = __builtin_amdgcn_mfma_f32_16x16x32_bf16(Ahi, Bhr, accI, 0, 0, 0);
            accI = __builtin_amdgcn_mfma_f32_16x16x32_bf16(Ahi, Blr, accI, 0, 0, 0);
            accI = __builtin_amdgcn_mfma_f32_16x16x32_bf16(Ali, Bhr, accI, 0, 0, 0);

            #pragma unroll
            for (int q = 0; q < 4; ++q)
                res[jj][nt][q] = make_float2(accP[q] - accN[q], accI[q]);
        }
    }
    __syncthreads();   // all xls reads done -> safe to alias as stg

    // ---- stage results: D col=lane&15 (o), row=(lane>>4)*4+q (bl); rows>=8 dropped ----
    if (ks < 2) {
        const int rbase = ks * 4, colo = lane & 15;
        #pragma unroll
        for (int jj = 0; jj < 4; ++jj)
            #pragma unroll
            for (int nt = 0; nt < 2; ++nt)
                #pragma unroll
                for (int q = 0; q < 4; ++q)
                    stg[(rbase + q) * 32 + nt * 16 + colo][wave * 4 + jj] = res[jj][nt][q];
    }
    __syncthreads();

    // ---- row-contiguous write-out: 256 rows x 33 float2, tail zeros fused ----
    float2* out2 = (float2*)out;
    #pragma unroll 2
    for (int t = 0; t < 33; ++t) {
        int idx = t * 256 + tid;              // [0, 8448)
        int row = idx / 33;                   // bl*32 + o
        int k = idx - row * 33;
        float2 v = (k < 16) ? stg[row][k] : make_float2(0.f, 0.f);
        long dst = ((long)(bl0 * 32 + row) * 64 + h) * 33 + k;
        out2[dst] = v;
    }
}

extern "C" void kernel_launch(void* const* d_in, const int* in_sizes, int n_in,
                              void* d_out, int out_size, void* d_ws, size_t ws_size,
                              hipStream_t stream) {
    const float* x_re  = (const float*)d_in[0];
    const float* x_im  = (const float*)d_in[1];
    const float* w1_re = (const float*)d_in[2];
    const float* w1_im = (const float*)d_in[3];
    const float* w2_re = (const float*)d_in[4];
    const float* w2_im = (const float*)d_in[5];
    float* out = (float*)d_out;
    char* ws = (char*)d_ws;

    w_prep<<<dim3(128), dim3(256), 0, stream>>>(w1_re, w1_im, w2_re, w2_im, ws);
    spectral_main<<<dim3(768), dim3(256), 0, stream>>>(x_re, x_im, out, ws);
}

// Round 10
// 33.983 us; speedup vs baseline: 3.5211x; 1.0205x over previous
//
#include <hip/hip_runtime.h>

#define HW 2112L            // 64*33
typedef float f32x4 __attribute__((ext_vector_type(4)));
typedef short s16x8 __attribute__((ext_vector_type(8)));

// ws: W B-fragment planes. 512 modes * 2 ntiles * 64 lanes * 8 bf16 * 2B = 1 MB/plane.
#define WT_PLANE 1048576L
#define OFF_WHR 0L
#define OFF_WLR (WT_PLANE)
#define OFF_WHI (2*WT_PLANE)
#define OFF_WLI (3*WT_PLANE)

__device__ __forceinline__ ushort f2bf(float f) {
    unsigned u = __float_as_uint(f);
    u += 0x7FFF + ((u >> 16) & 1);          // RNE to bf16
    return (ushort)(u >> 16);
}
__device__ __forceinline__ void split_bf(float v, ushort& hi, ushort& lo) {
    hi = f2bf(v);
    float hf = __uint_as_float(((unsigned)hi) << 16);
    lo = f2bf(v - hf);
}

// =============== K1: W -> B-frag planes (64 blocks) + middle-band fill (1984 blocks) ===============
// w-role block=(r,i,nt); thread=(col=tid>>4, j=tid&15) -> j-fastest coalesced reads
// (64B runs), zero fetch amplification. Fill role streams the h-in-[16,48) band.
__global__ __launch_bounds__(256) void k1_prep_fill(
    const float* __restrict__ w1_re, const float* __restrict__ w1_im,
    const float* __restrict__ w2_re, const float* __restrict__ w2_im,
    float* __restrict__ out, char* __restrict__ ws)
{
    const int tid = threadIdx.x, bid = blockIdx.x;

    if (bid >= 64) {
        // ---- fill role: middle band h in [16,48) ----
        const int fid = bid - 64;                 // [0,1984)
        int gtid = fid * 256 + tid, n = 1984 * 256;
        float4* out4 = (float4*)out;
        const float4 z = make_float4(0.f, 0.f, 0.f, 0.f);
        for (int idx = gtid; idx < 4096 * 528; idx += n) {
            int plane = idx / 528;
            int k = idx - plane * 528;
            out4[(long)plane * 1056 + 264 + k] = z;
        }
        return;
    }

    const int r = bid >> 5, i = (bid >> 1) & 15, nt = bid & 1;
    const float* wre = r ? w2_re : w1_re;
    const float* wim = r ? w2_im : w1_im;
    const int col = tid >> 4, j = tid & 15, o = nt * 16 + col;
    const int modeLin = (r * 16 + i) * 16 + j;
    s16x8* phr = (s16x8*)(ws + OFF_WHR);
    s16x8* plr = (s16x8*)(ws + OFF_WLR);
    s16x8* phi = (s16x8*)(ws + OFF_WHI);
    s16x8* pli = (s16x8*)(ws + OFF_WLI);
    #pragma unroll
    for (int kg = 0; kg < 4; ++kg) {
        s16x8 hr, lr, hi2, li2;
        #pragma unroll
        for (int e = 0; e < 8; ++e) {
            int c = kg * 8 + e;
            long src = ((long)(c * 32 + o) * 16 + i) * 16 + j;
            ushort a, b;
            split_bf(wre[src], a, b); hr[e] = (short)a; lr[e] = (short)b;
            split_bf(wim[src], a, b); hi2[e] = (short)a; li2[e] = (short)b;
        }
        long off = (long)(modeLin * 2 + nt) * 64 + kg * 16 + col;
        phr[off] = hr; plr[off] = lr; phi[off] = hi2; pli[off] = li2;
    }
}

// =============== K2: compute only. 1024 blocks=(r,i,bt), bltile=4, 4 blocks/CU ===============
__global__ __launch_bounds__(256, 4) void k2_compute(
    const float* __restrict__ x_re, const float* __restrict__ x_im,
    float* __restrict__ out, const char* __restrict__ ws)
{
    const int tid = threadIdx.x, bid = blockIdx.x;
    const int r = bid >> 9, i = (bid >> 5) & 15, bt = bid & 31;
    const int h = r ? 48 + i : i;
    const int bl0 = bt * 4;
    const int modeBase = (r * 16 + i) * 16;

    // xls: flat float2, addr = c*69 + bl*17 + j  (odd c-stride -> <=2-way LDS conflicts)
    __shared__ __align__(16) float2 xls[2206];     // 17.6 KB
    __shared__ __align__(16) float2 stg[128][17];  // 17.4 KB

    // ---- stage x[bl0..+4, all c, h, j<16]: 2 steps x 8 scalar loads, 64B-coalesced ----
    #pragma unroll
    for (int p = 0; p < 2; ++p) {
        int idx = p * 256 + tid;            // [0,512)
        int j4 = idx & 3, row = idx >> 2;   // row: c=row>>2, bl=row&3
        int c = row >> 2, bl = row & 3;
        long base = ((long)((bl0 + bl) * 32 + c)) * HW + h * 33 + j4 * 4;
        float r0 = x_re[base + 0], r1 = x_re[base + 1], r2 = x_re[base + 2], r3 = x_re[base + 3];
        float i0 = x_im[base + 0], i1 = x_im[base + 1], i2 = x_im[base + 2], i3 = x_im[base + 3];
        int la = c * 69 + bl * 17 + j4 * 4;
        xls[la + 0] = make_float2(r0, i0);
        xls[la + 1] = make_float2(r1, i1);
        xls[la + 2] = make_float2(r2, i2);
        xls[la + 3] = make_float2(r3, i3);
    }
    __syncthreads();

    const int wave = tid >> 6, lane = tid & 63;
    const int m = lane & 3, ks = lane >> 4, colo = lane & 15;

    const s16x8* Bwhr = (const s16x8*)(ws + OFF_WHR);
    const s16x8* Bwlr = (const s16x8*)(ws + OFF_WLR);
    const s16x8* Bwhi = (const s16x8*)(ws + OFF_WHI);
    const s16x8* Bwli = (const s16x8*)(ws + OFF_WLI);

    #pragma unroll
    for (int jj = 0; jj < 4; ++jj) {
        const int j = wave * 4 + jj;
        const int modeLin = modeBase + j;

        // ---- issue B-frag loads first (L2 latency hides under split VALU below) ----
        s16x8 Bhr[2], Blr[2], Bhi[2], Bli[2];
        #pragma unroll
        for (int nt = 0; nt < 2; ++nt) {
            long boff = (long)(modeLin * 2 + nt) * 64 + lane;
            Bhr[nt] = Bwhr[boff]; Blr[nt] = Bwlr[boff];
            Bhi[nt] = Bwhi[boff]; Bli[nt] = Bwli[boff];
        }

        // ---- gather A-frags from LDS (bl=m, c=ks*8+e), split to bf16 hi/lo ----
        s16x8 Ahr, Alr, Ahi, Ali;
        #pragma unroll
        for (int e = 0; e < 8; ++e) {
            float2 v = xls[(ks * 8 + e) * 69 + m * 17 + j];
            ushort a, b;
            split_bf(v.x, a, b); Ahr[e] = (short)a; Alr[e] = (short)b;
            split_bf(v.y, a, b); Ahi[e] = (short)a; Ali[e] = (short)b;
        }

        #pragma unroll
        for (int nt = 0; nt < 2; ++nt) {
            f32x4 accP = (f32x4)0.0f, accN = (f32x4)0.0f, accI = (f32x4)0.0f;
            accP = __builtin_amdgcn_mfma_f32_16x16x32_bf16(Ahr, Bhr[nt], accP, 0, 0, 0);
            accP = __builtin_amdgcn_mfma_f32_16x16x32_bf16(Ahr, Blr[nt], accP, 0, 0, 0);
            accP = __builtin_amdgcn_mfma_f32_16x16x32_bf16(Alr, Bhr[nt], accP, 0, 0, 0);
            accN = __builtin_amdgcn_mfma_f32_16x16x32_bf16(Ahi, Bhi[nt], accN, 0, 0, 0);
            accN = __builtin_amdgcn_mfma_f32_16x16x32_bf16(Ahi, Bli[nt], accN, 0, 0, 0);
            accN = __builtin_amdgcn_mfma_f32_16x16x32_bf16(Ali, Bhi[nt], accN, 0, 0, 0);
            accI = __builtin_amdgcn_mfma_f32_16x16x32_bf16(Ahr, Bhi[nt], accI, 0, 0, 0);
            accI = __builtin_amdgcn_mfma_f32_16x16x32_bf16(Ahr, Bli[nt], accI, 0, 0, 0);
            accI = __builtin_amdgcn_mfma_f32_16x16x32_bf16(Alr, Bhi[nt], accI, 0, 0, 0);
            accI = __builtin_amdgcn_mfma_f32_16x16x32_bf16(Ahi, Bhr[nt], accI, 0, 0, 0);
            accI = __builtin_amdgcn_mfma_f32_16x16x32_bf16(Ahi, Blr[nt], accI, 0, 0, 0);
            accI = __builtin_amdgcn_mfma_f32_16x16x32_bf16(Ali, Bhr[nt], accI, 0, 0, 0);

            // D: col=lane&15 (o), row=ks*4+q (bl=q); rows repeat every 4 -> lanes 0-15 store
            if (ks == 0) {
                #pragma unroll
                for (int q = 0; q < 4; ++q)
                    stg[q * 32 + nt * 16 + colo][j] =
                        make_float2(accP[q] - accN[q], accI[q]);
            }
        }
    }
    __syncthreads();

    // ---- row-contiguous write-out: 128 rows x 33 float2, tail zeros fused ----
    float2* out2 = (float2*)out;
    #pragma unroll 2
    for (int t = 0; t < 17; ++t) {
        int idx = t * 256 + tid;              // [0, 4352); valid < 4224
        if (idx < 128 * 33) {
            int row = idx / 33;               // bl*32 + o
            int k = idx - row * 33;
            float2 v = (k < 16) ? stg[row][k] : make_float2(0.f, 0.f);
            long dst = ((long)(bl0 * 32 + row) * 64 + h) * 33 + k;
            out2[dst] = v;
        }
    }
}

extern "C" void kernel_launch(void* const* d_in, const int* in_sizes, int n_in,
                              void* d_out, int out_size, void* d_ws, size_t ws_size,
                              hipStream_t stream) {
    const float* x_re  = (const float*)d_in[0];
    const float* x_im  = (const float*)d_in[1];
    const float* w1_re = (const float*)d_in[2];
    const float* w1_im = (const float*)d_in[3];
    const float* w2_re = (const float*)d_in[4];
    const float* w2_im = (const float*)d_in[5];
    float* out = (float*)d_out;
    char* ws = (char*)d_ws;

    k1_prep_fill<<<dim3(2048), dim3(256), 0, stream>>>(
        w1_re, w1_im, w2_re, w2_im, out, ws);
    k2_compute<<<dim3(1024), dim3(256), 0, stream>>>(x_re, x_im, out, ws);
}